// Round 1
// baseline (1190.377 us; speedup 1.0000x reference)
//
#include <hip/hip_runtime.h>
#include <math.h>

#define N0V 500000
#define N1V 50000
#define N2V 4096
#define E0V 1280000
#define E1V 40960
#define INF 128
#define HIDF 256
#define OUTF 47

// ---------------- layer 0 scatter-sum (atomics) ----------------
__global__ __launch_bounds__(256) void scatter0_k(
    const float* __restrict__ x, const int* __restrict__ src,
    const int* __restrict__ dst, float* __restrict__ agg,
    float* __restrict__ cnt) {
  long long gid = (long long)blockIdx.x * 256 + threadIdx.x;
  const long long total = (long long)E0V * INF;
  if (gid >= total) return;
  int e = (int)(gid >> 7);
  int c = (int)(gid & (INF - 1));
  int s = src[e];
  int d = dst[e];
  atomicAdd(&agg[d * INF + c], x[s * INF + c]);
  if (c == 0) atomicAdd(&cnt[d], 1.0f);
}

// ---------------- layer 0 dense: h = relu(mean@Wl + bl + x@Wr) ----------------
// 16 rows per block, 256 threads; thread j owns output column j.
__global__ __launch_bounds__(256) void dense0_k(
    const float* __restrict__ agg, const float* __restrict__ cnt,
    const float* __restrict__ x, const float* __restrict__ Wl,
    const float* __restrict__ bl, const float* __restrict__ Wr,
    float* __restrict__ h) {
  __shared__ float a_s[16 * 128];
  __shared__ float x_s[16 * 128];
  __shared__ float rinv_s[16];
  const int tid = threadIdx.x;
  const int base = blockIdx.x * 16;

  if (tid < 16) {
    float c = cnt[base + tid];
    rinv_s[tid] = 1.0f / fmaxf(c, 1.0f);
  }
  __syncthreads();

  for (int idx = tid; idx < 16 * 128; idx += 256) {
    int rr = idx >> 7;
    int k = idx & 127;
    a_s[idx] = agg[(base + rr) * 128 + k] * rinv_s[rr];
    x_s[idx] = x[(base + rr) * 128 + k];
  }
  __syncthreads();

  const int j = tid;  // 0..255 output column
  float acc[16];
#pragma unroll
  for (int rr = 0; rr < 16; rr++) acc[rr] = 0.0f;

  for (int k = 0; k < 128; k++) {
    float wl = Wl[k * 256 + j];
    float wr = Wr[k * 256 + j];
#pragma unroll
    for (int rr = 0; rr < 16; rr++)
      acc[rr] += a_s[rr * 128 + k] * wl + x_s[rr * 128 + k] * wr;
  }

  float b = bl[j];
#pragma unroll
  for (int rr = 0; rr < 16; rr++)
    h[(base + rr) * 256 + j] = fmaxf(acc[rr] + b, 0.0f);
}

// ---------------- layer 1 scatter-sum ----------------
__global__ __launch_bounds__(256) void scatter1_k(
    const float* __restrict__ h, const int* __restrict__ src,
    const int* __restrict__ dst, float* __restrict__ agg,
    float* __restrict__ cnt) {
  int gid = blockIdx.x * 256 + threadIdx.x;
  const int total = E1V * HIDF;
  if (gid >= total) return;
  int e = gid >> 8;
  int c = gid & (HIDF - 1);
  int s = src[e];
  int d = dst[e];
  atomicAdd(&agg[d * HIDF + c], h[s * HIDF + c]);
  if (c == 0) atomicAdd(&cnt[d], 1.0f);
}

// ---------------- layer 1 dense + log_softmax ----------------
// one wave (64 lanes) per output row; lanes 0..46 own a column.
__global__ __launch_bounds__(64) void final_k(
    const float* __restrict__ agg, const float* __restrict__ cnt,
    const float* __restrict__ h, const float* __restrict__ Wl,
    const float* __restrict__ bl, const float* __restrict__ Wr,
    float* __restrict__ out) {
  __shared__ float a_s[256];
  __shared__ float h_s[256];
  const int i = blockIdx.x;
  const int lane = threadIdx.x;

  float rinv = 1.0f / fmaxf(cnt[i], 1.0f);
  for (int k = lane; k < 256; k += 64) {
    a_s[k] = agg[i * 256 + k] * rinv;
    h_s[k] = h[i * 256 + k];
  }
  __syncthreads();

  float val = -INFINITY;
  if (lane < OUTF) {
    float acc = bl[lane];
    for (int k = 0; k < 256; k++)
      acc += a_s[k] * Wl[k * OUTF + lane] + h_s[k] * Wr[k * OUTF + lane];
    val = acc;
  }

  // wave-wide max
  float m = val;
  for (int off = 32; off >= 1; off >>= 1) m = fmaxf(m, __shfl_xor(m, off, 64));
  float ex = (lane < OUTF) ? expf(val - m) : 0.0f;
  float ssum = ex;
  for (int off = 32; off >= 1; off >>= 1) ssum += __shfl_xor(ssum, off, 64);

  if (lane < OUTF) out[i * OUTF + lane] = val - m - logf(ssum);
}

extern "C" void kernel_launch(void* const* d_in, const int* in_sizes, int n_in,
                              void* d_out, int out_size, void* d_ws, size_t ws_size,
                              hipStream_t stream) {
  const float* x   = (const float*)d_in[0];
  const float* Wl0 = (const float*)d_in[1];
  const float* bl0 = (const float*)d_in[2];
  const float* Wr0 = (const float*)d_in[3];
  const float* Wl1 = (const float*)d_in[4];
  const float* bl1 = (const float*)d_in[5];
  const float* Wr1 = (const float*)d_in[6];
  const int* src0  = (const int*)d_in[7];
  const int* dst0  = (const int*)d_in[8];
  const int* src1  = (const int*)d_in[9];
  const int* dst1  = (const int*)d_in[10];
  float* out = (float*)d_out;

  // workspace layout (bytes):
  //   agg0: 50000*128*4 = 25,600,000   @ 0
  //   cnt0: 50000*4     =    200,000   @ 25,600,000
  //   agg1: 4096*256*4  =  4,194,304   @ 25,800,000
  //   cnt1: 4096*4      =     16,384   @ 29,994,304
  //   h   : 50000*256*4 = 51,200,000   @ 30,010,688
  char* ws = (char*)d_ws;
  float* agg0 = (float*)(ws);
  float* cnt0 = (float*)(ws + 25600000);
  float* agg1 = (float*)(ws + 25800000);
  float* cnt1 = (float*)(ws + 29994304);
  float* h    = (float*)(ws + 30010688);

  // zero all accumulators in one shot (they are contiguous)
  hipMemsetAsync(ws, 0, 30010688, stream);

  {
    long long total = (long long)E0V * INF;
    int blocks = (int)((total + 255) / 256);
    scatter0_k<<<blocks, 256, 0, stream>>>(x, src0, dst0, agg0, cnt0);
  }

  dense0_k<<<N1V / 16, 256, 0, stream>>>(agg0, cnt0, x, Wl0, bl0, Wr0, h);

  {
    int total = E1V * HIDF;
    scatter1_k<<<(total + 255) / 256, 256, 0, stream>>>(h, src1, dst1, agg1, cnt1);
  }

  final_k<<<N2V, 64, 0, stream>>>(agg1, cnt1, h, Wl1, bl1, Wr1, out);
}

// Round 2
// 908.713 us; speedup vs baseline: 1.3100x; 1.3100x over previous
//
#include <hip/hip_runtime.h>
#include <math.h>

#define N0V 500000
#define N1V 50000
#define N2V 4096
#define E0V 1280000
#define E1V 40960
#define INF 128
#define HIDF 256
#define OUTF 47

// ---------------- CSR build: histogram ----------------
__global__ __launch_bounds__(256) void hist_k(
    const int* __restrict__ dst0, const int* __restrict__ dst1,
    int* __restrict__ hist0, int* __restrict__ hist1) {
  int gid = blockIdx.x * 256 + threadIdx.x;
  if (gid < E0V) {
    atomicAdd(&hist0[dst0[gid]], 1);
  } else if (gid < E0V + E1V) {
    atomicAdd(&hist1[dst1[gid - E0V]], 1);
  }
}

// ---------------- CSR build: prefix scan (single block) ----------------
__global__ __launch_bounds__(1024) void scan_k(
    const int* __restrict__ hist0, const int* __restrict__ hist1,
    int* __restrict__ off0, int* __restrict__ cur0,
    int* __restrict__ off1, int* __restrict__ cur1) {
  __shared__ int sums[1024];
  const int t = threadIdx.x;
  // ---- part 0: N=50000, chunk=49 per thread ----
  {
    const int N = 50000, C = 49;
    int lo = t * C;
    int hi = lo + C; if (hi > N) hi = N;
    int s = 0;
    for (int i = lo; i < hi; i++) s += hist0[i];
    sums[t] = s;
    __syncthreads();
    for (int off = 1; off < 1024; off <<= 1) {
      int v = (t >= off) ? sums[t - off] : 0;
      __syncthreads();
      sums[t] += v;
      __syncthreads();
    }
    int run = sums[t] - s;  // exclusive
    for (int i = lo; i < hi; i++) {
      off0[i] = run; cur0[i] = run;
      run += hist0[i];
    }
    if (t == 1023) off0[N] = sums[1023];
    __syncthreads();
  }
  // ---- part 1: N=4096, chunk=4 per thread ----
  {
    const int N = 4096, C = 4;
    int lo = t * C;
    int hi = lo + C; if (hi > N) hi = N;
    int s = 0;
    for (int i = lo; i < hi; i++) s += hist1[i];
    sums[t] = s;
    __syncthreads();
    for (int off = 1; off < 1024; off <<= 1) {
      int v = (t >= off) ? sums[t - off] : 0;
      __syncthreads();
      sums[t] += v;
      __syncthreads();
    }
    int run = sums[t] - s;
    for (int i = lo; i < hi; i++) {
      off1[i] = run; cur1[i] = run;
      run += hist1[i];
    }
    if (t == 1023) off1[N] = sums[1023];
  }
}

// ---------------- CSR build: scatter edge source ids ----------------
__global__ __launch_bounds__(256) void scatteridx_k(
    const int* __restrict__ src0, const int* __restrict__ dst0,
    const int* __restrict__ src1, const int* __restrict__ dst1,
    int* __restrict__ cur0, int* __restrict__ cur1,
    int* __restrict__ esrc0, int* __restrict__ esrc1) {
  int gid = blockIdx.x * 256 + threadIdx.x;
  if (gid < E0V) {
    int pos = atomicAdd(&cur0[dst0[gid]], 1);
    esrc0[pos] = src0[gid];
  } else if (gid < E0V + E1V) {
    int g = gid - E0V;
    int pos = atomicAdd(&cur1[dst1[g]], 1);
    esrc1[pos] = src1[g];
  }
}

// ---------------- layer 0: fused gather-mean + dense + relu ----------------
// 16 target rows per block; 4 waves, each wave gathers 4 rows; then
// thread j (0..255) owns output column j for all 16 rows.
__global__ __launch_bounds__(256) void dense0_fused(
    const float* __restrict__ x, const int* __restrict__ off0,
    const int* __restrict__ esrc0, const float* __restrict__ Wl,
    const float* __restrict__ bl, const float* __restrict__ Wr,
    float* __restrict__ h) {
  __shared__ float a_s[16 * 128];
  __shared__ float x_s[16 * 128];
  const int tid = threadIdx.x;
  const int base = blockIdx.x * 16;
  const int wave = tid >> 6;
  const int lane = tid & 63;

  // target features: rows base..base+15 are contiguous in x
  for (int idx = tid; idx < 16 * 128; idx += 256)
    x_s[idx] = x[base * 128 + idx];

  // gather-mean: wave handles rows wave*4 .. wave*4+3
  for (int q = 0; q < 4; q++) {
    int r = wave * 4 + q;
    int row = base + r;
    int s0 = off0[row];
    int n = off0[row + 1] - s0;
    float acc0 = 0.f, acc1 = 0.f;
    for (int c0 = 0; c0 < n; c0 += 64) {
      int m = n - c0; if (m > 64) m = 64;
      int myid = (lane < m) ? esrc0[s0 + c0 + lane] : 0;
      for (int j = 0; j < m; j++) {
        int sid = __shfl(myid, j, 64);
        const float* xr = x + sid * INF;
        acc0 += xr[lane];
        acc1 += xr[lane + 64];
      }
    }
    float rinv = 1.f / fmaxf((float)n, 1.f);
    a_s[r * 128 + lane] = acc0 * rinv;
    a_s[r * 128 + lane + 64] = acc1 * rinv;
  }
  __syncthreads();

  const int j = tid;
  float acc[16];
#pragma unroll
  for (int rr = 0; rr < 16; rr++) acc[rr] = 0.0f;

  for (int k = 0; k < 128; k++) {
    float wl = Wl[k * 256 + j];
    float wr = Wr[k * 256 + j];
#pragma unroll
    for (int rr = 0; rr < 16; rr++)
      acc[rr] += a_s[rr * 128 + k] * wl + x_s[rr * 128 + k] * wr;
  }

  float b = bl[j];
#pragma unroll
  for (int rr = 0; rr < 16; rr++)
    h[(base + rr) * 256 + j] = fmaxf(acc[rr] + b, 0.0f);
}

// ---------------- layer 1: fused gather-mean + dense + log_softmax ----------------
// one wave per output row
__global__ __launch_bounds__(64) void final_fused(
    const float* __restrict__ h, const int* __restrict__ off1,
    const int* __restrict__ esrc1, const float* __restrict__ Wl,
    const float* __restrict__ bl, const float* __restrict__ Wr,
    float* __restrict__ out) {
  __shared__ float a_s[256];
  __shared__ float h_s[256];
  const int i = blockIdx.x;
  const int lane = threadIdx.x;

  int s0 = off1[i];
  int n = off1[i + 1] - s0;
  float acc0 = 0.f, acc1 = 0.f, acc2 = 0.f, acc3 = 0.f;
  for (int c0 = 0; c0 < n; c0 += 64) {
    int m = n - c0; if (m > 64) m = 64;
    int myid = (lane < m) ? esrc1[s0 + c0 + lane] : 0;
    for (int j = 0; j < m; j++) {
      int sid = __shfl(myid, j, 64);
      const float* hr = h + sid * HIDF;
      acc0 += hr[lane];
      acc1 += hr[lane + 64];
      acc2 += hr[lane + 128];
      acc3 += hr[lane + 192];
    }
  }
  float rinv = 1.f / fmaxf((float)n, 1.f);
  a_s[lane] = acc0 * rinv;
  a_s[lane + 64] = acc1 * rinv;
  a_s[lane + 128] = acc2 * rinv;
  a_s[lane + 192] = acc3 * rinv;
  const float* ht = h + i * HIDF;
  h_s[lane] = ht[lane];
  h_s[lane + 64] = ht[lane + 64];
  h_s[lane + 128] = ht[lane + 128];
  h_s[lane + 192] = ht[lane + 192];
  __syncthreads();

  float val = -INFINITY;
  if (lane < OUTF) {
    float acc = bl[lane];
    for (int k = 0; k < 256; k++)
      acc += a_s[k] * Wl[k * OUTF + lane] + h_s[k] * Wr[k * OUTF + lane];
    val = acc;
  }

  float m = val;
  for (int off = 32; off >= 1; off >>= 1) m = fmaxf(m, __shfl_xor(m, off, 64));
  float ex = (lane < OUTF) ? expf(val - m) : 0.0f;
  float ssum = ex;
  for (int off = 32; off >= 1; off >>= 1) ssum += __shfl_xor(ssum, off, 64);

  if (lane < OUTF) out[i * OUTF + lane] = val - m - logf(ssum);
}

extern "C" void kernel_launch(void* const* d_in, const int* in_sizes, int n_in,
                              void* d_out, int out_size, void* d_ws, size_t ws_size,
                              hipStream_t stream) {
  const float* x   = (const float*)d_in[0];
  const float* Wl0 = (const float*)d_in[1];
  const float* bl0 = (const float*)d_in[2];
  const float* Wr0 = (const float*)d_in[3];
  const float* Wl1 = (const float*)d_in[4];
  const float* bl1 = (const float*)d_in[5];
  const float* Wr1 = (const float*)d_in[6];
  const int* src0  = (const int*)d_in[7];
  const int* dst0  = (const int*)d_in[8];
  const int* src1  = (const int*)d_in[9];
  const int* dst1  = (const int*)d_in[10];
  float* out = (float*)d_out;

  // workspace layout (bytes, 256-aligned):
  //   hist0 @ 0         200,000
  //   hist1 @ 200,064    16,384   (memset covers [0, 216,448))
  //   off0  @ 216,576   200,004
  //   cur0  @ 416,768   200,000
  //   off1  @ 616,960    16,388
  //   cur1  @ 633,600    16,384
  //   esrc0 @ 650,240  5,120,000
  //   esrc1 @ 5,770,240  163,840
  //   h     @ 5,934,080 51,200,000  (end 57,134,080)
  char* ws = (char*)d_ws;
  int* hist0 = (int*)(ws);
  int* hist1 = (int*)(ws + 200064);
  int* off0  = (int*)(ws + 216576);
  int* cur0  = (int*)(ws + 416768);
  int* off1  = (int*)(ws + 616960);
  int* cur1  = (int*)(ws + 633600);
  int* esrc0 = (int*)(ws + 650240);
  int* esrc1 = (int*)(ws + 5770240);
  float* h   = (float*)(ws + 5934080);

  hipMemsetAsync(ws, 0, 216448, stream);

  const int gridE = (E0V + E1V + 255) / 256;
  hist_k<<<gridE, 256, 0, stream>>>(dst0, dst1, hist0, hist1);
  scan_k<<<1, 1024, 0, stream>>>(hist0, hist1, off0, cur0, off1, cur1);
  scatteridx_k<<<gridE, 256, 0, stream>>>(src0, dst0, src1, dst1,
                                          cur0, cur1, esrc0, esrc1);
  dense0_fused<<<N1V / 16, 256, 0, stream>>>(x, off0, esrc0, Wl0, bl0, Wr0, h);
  final_fused<<<N2V, 64, 0, stream>>>(h, off1, esrc1, Wl1, bl1, Wr1, out);
}